// Round 4
// baseline (869.939 us; speedup 1.0000x reference)
//
#include <hip/hip_runtime.h>
#include <stdint.h>

#define N_NODES 100000
#define N_EDGES 1600000
#define NFEAT 256
#define NHID 64
#define TILE 128                              // dst nodes per bucket
#define NBKT ((N_NODES + TILE - 1) / TILE)    // 782
#define CPAD 16                               // cursor padding: 16 ints = 64B line

// ---------------------------------------------------------------------------
// fp32 -> bf16 (round to nearest even)
// ---------------------------------------------------------------------------
__device__ __forceinline__ unsigned short f2bf(float f) {
  unsigned u = __float_as_uint(f);
  u = (u + 0x7FFFu + ((u >> 16) & 1u)) >> 16;
  return (unsigned short)u;
}

// ---------------------------------------------------------------------------
// Kernel 1: support = x @ W  [100000,256] x [256,64], fp32 math, bf16 output
// ---------------------------------------------------------------------------
__global__ __launch_bounds__(256, 2) void gcn_gemm(const float* __restrict__ x,
                                                   const float* __restrict__ W,
                                                   unsigned short* __restrict__ support) {
  __shared__ float xs[64][NFEAT + 4];
  const int tid = threadIdx.x;
  const int row0 = blockIdx.x * 64;

#pragma unroll
  for (int it = 0; it < 16; ++it) {
    int idx = it * 256 + tid;
    int r = idx >> 6;
    int kc = (idx & 63) << 2;
    float4 v = make_float4(0.f, 0.f, 0.f, 0.f);
    if (row0 + r < N_NODES)
      v = *reinterpret_cast<const float4*>(&x[(size_t)(row0 + r) * NFEAT + kc]);
    *reinterpret_cast<float4*>(&xs[r][kc]) = v;
  }
  __syncthreads();

  const int c4 = (tid & 15) << 2;
  const int r4 = (tid >> 4) << 2;
  float acc[4][4];
#pragma unroll
  for (int i = 0; i < 4; ++i)
#pragma unroll
    for (int j = 0; j < 4; ++j) acc[i][j] = 0.f;

  for (int kb = 0; kb < NFEAT; kb += 4) {
    float wv[4][4];
#pragma unroll
    for (int j = 0; j < 4; ++j) {
      float4 t = *reinterpret_cast<const float4*>(&W[(kb + j) * NHID + c4]);
      wv[j][0] = t.x; wv[j][1] = t.y; wv[j][2] = t.z; wv[j][3] = t.w;
    }
    float xv[4][4];
#pragma unroll
    for (int i = 0; i < 4; ++i) {
      float4 t = *reinterpret_cast<const float4*>(&xs[r4 + i][kb]);
      xv[i][0] = t.x; xv[i][1] = t.y; xv[i][2] = t.z; xv[i][3] = t.w;
    }
#pragma unroll
    for (int i = 0; i < 4; ++i)
#pragma unroll
      for (int c = 0; c < 4; ++c)
#pragma unroll
        for (int j = 0; j < 4; ++j)
          acc[i][c] = fmaf(xv[i][j], wv[j][c], acc[i][c]);
  }

#pragma unroll
  for (int i = 0; i < 4; ++i) {
    int r = row0 + r4 + i;
    if (r < N_NODES) {
      ushort4 o;
      o.x = f2bf(acc[i][0]); o.y = f2bf(acc[i][1]);
      o.z = f2bf(acc[i][2]); o.w = f2bf(acc[i][3]);
      *reinterpret_cast<ushort4*>(&support[(size_t)r * NHID + c4]) = o;
    }
  }
}

// ---------------------------------------------------------------------------
// Bucket histogram: LDS pre-aggregation, then one global atomic per
// (block, nonempty bucket). Counters padded to one per 64B line.
// ---------------------------------------------------------------------------
__global__ __launch_bounds__(256) void gcn_bhist(const int* __restrict__ edst,
                                                 int* __restrict__ bcnt) {
  __shared__ int h[NBKT];
  for (int i = threadIdx.x; i < NBKT; i += 256) h[i] = 0;
  __syncthreads();
  const int stride = gridDim.x * 256;
  for (int e = blockIdx.x * 256 + threadIdx.x; e < N_EDGES; e += stride)
    atomicAdd(&h[edst[e] >> 7], 1);
  __syncthreads();
  for (int i = threadIdx.x; i < NBKT; i += 256) {
    int v = h[i];
    if (v) atomicAdd(&bcnt[i * CPAD], v);
  }
}

// ---------------------------------------------------------------------------
// One-block exclusive scan over NBKT (<=1024) bucket counts
// ---------------------------------------------------------------------------
__global__ __launch_bounds__(1024) void gcn_bscan(const int* __restrict__ bcnt,
                                                  int* __restrict__ offs,
                                                  int* __restrict__ cur) {
  __shared__ int sh[1024];
  const int t = threadIdx.x;
  int v = (t < NBKT) ? bcnt[t * CPAD] : 0;
  sh[t] = v;
  __syncthreads();
  for (int s = 1; s < 1024; s <<= 1) {
    int a = (t >= s) ? sh[t - s] : 0;
    __syncthreads();
    sh[t] += a;
    __syncthreads();
  }
  if (t < NBKT) {
    int excl = sh[t] - v;
    offs[t] = excl;
    cur[t * CPAD] = excl;
    if (t == NBKT - 1) offs[NBKT] = sh[t];
  }
}

// ---------------------------------------------------------------------------
// Bucket fill: 782 clustered write fronts instead of 100K random slots.
// rec.x packs src (17 bits) | dst-low-7 << 17 ; rec.y = weight bits
// ---------------------------------------------------------------------------
__global__ __launch_bounds__(256) void gcn_bfill(const int* __restrict__ esrc,
                                                 const int* __restrict__ edst,
                                                 const float* __restrict__ ew,
                                                 int* __restrict__ cur,
                                                 int2* __restrict__ rec) {
  int e = blockIdx.x * 256 + threadIdx.x;
  if (e >= N_EDGES) return;
  int d = edst[e];
  int b = d >> 7;
  int slot = atomicAdd(&cur[b * CPAD], 1);
  rec[slot] = make_int2(esrc[e] | ((d & (TILE - 1)) << 17), __float_as_int(ew[e]));
}

// ---------------------------------------------------------------------------
// Threefry-2x32-20, key (0,42), counter (0,i); keep iff top bit of x0^x1 clear
// ---------------------------------------------------------------------------
__device__ __forceinline__ unsigned rotl32(unsigned x, int r) {
  return (x << r) | (x >> (32 - r));
}

__device__ __forceinline__ unsigned threefry_bits(unsigned i) {
  const unsigned ks0 = 0u, ks1 = 42u;
  const unsigned ks2 = 0x1BD11BDAu ^ ks0 ^ ks1;
  unsigned x0 = ks0;
  unsigned x1 = i + ks1;
#define TF_R4(a, bb, c, d)                       \
  x0 += x1; x1 = rotl32(x1, a);  x1 ^= x0;       \
  x0 += x1; x1 = rotl32(x1, bb); x1 ^= x0;       \
  x0 += x1; x1 = rotl32(x1, c);  x1 ^= x0;       \
  x0 += x1; x1 = rotl32(x1, d);  x1 ^= x0;
  TF_R4(13, 15, 26, 6);  x0 += ks1; x1 += ks2 + 1u;
  TF_R4(17, 29, 16, 24); x0 += ks2; x1 += ks0 + 2u;
  TF_R4(13, 15, 26, 6);  x0 += ks0; x1 += ks1 + 3u;
  TF_R4(17, 29, 16, 24); x0 += ks1; x1 += ks2 + 4u;
  TF_R4(13, 15, 26, 6);  x0 += ks2; x1 += ks0 + 5u;
#undef TF_R4
  return x0 ^ x1;
}

// ---------------------------------------------------------------------------
// Bucket accumulate + fused epilogue. One block per 128-node bucket:
// 32KB LDS fp32 accumulator, half-wave (32 lanes) per edge:
//   lane l gathers bf16 feat pair (2l, 2l+1) of support[src], scales by w,
//   LDS-atomic-adds into interleaved layout [row][(f&1)*32 + (f>>1)]
//   (conflict-free: 32 lanes hit banks 0..31).
// Epilogue: bias + relu + threefry dropout, coalesced store.
// ---------------------------------------------------------------------------
__global__ __launch_bounds__(256, 2) void gcn_baccum(const unsigned* __restrict__ support2,
                                                     const int* __restrict__ offs,
                                                     const int2* __restrict__ rec,
                                                     const float* __restrict__ bias,
                                                     float* __restrict__ out) {
  __shared__ float acc[TILE][NHID];
  const int t = threadIdx.x;
  for (int i = t; i < TILE * NHID; i += 256) ((float*)acc)[i] = 0.f;
  __syncthreads();

  const int bkt = blockIdx.x;
  const int beg = offs[bkt], end = offs[bkt + 1];
  const int hw = t >> 5;   // 0..7, half-wave id
  const int l = t & 31;

  for (int j = beg + hw; j < end; j += 8) {
    int2 r = rec[j];
    int src = r.x & 0x1FFFF;
    int dl = (r.x >> 17) & (TILE - 1);
    float w = __int_as_float(r.y);
    unsigned p = support2[(size_t)src * 32 + l];
    float v0 = __uint_as_float(p << 16) * w;          // feat 2l
    float v1 = __uint_as_float(p & 0xFFFF0000u) * w;  // feat 2l+1
    atomicAdd(&acc[dl][l], v0);        // even feats at words 0..31
    atomicAdd(&acc[dl][32 + l], v1);   // odd feats at words 32..63
  }
  __syncthreads();

  const int row0 = bkt * TILE;
  const int col = t & 63;
  const float bb = bias[col];
  const int widx = ((col & 1) << 5) + (col >> 1);  // de-interleave
  for (int r = t >> 6; r < TILE; r += 4) {
    int node = row0 + r;
    if (node >= N_NODES) break;
    float h = fmaxf(acc[r][widx] + bb, 0.f) * 2.0f;
    unsigned i = (unsigned)node * 64u + (unsigned)col;
    unsigned m = threefry_bits(i);
    out[i] = (m & 0x80000000u) ? 0.f : h;
  }
}

// ---------------------------------------------------------------------------
extern "C" void kernel_launch(void* const* d_in, const int* in_sizes, int n_in,
                              void* d_out, int out_size, void* d_ws, size_t ws_size,
                              hipStream_t stream) {
  const float* x = (const float*)d_in[0];
  const float* W = (const float*)d_in[1];
  const float* b = (const float*)d_in[2];
  const int* esrc = (const int*)d_in[3];
  const int* edst = (const int*)d_in[4];
  const float* ew = (const float*)d_in[5];
  float* out = (float*)d_out;

  char* ws = (char*)d_ws;
  unsigned short* support = (unsigned short*)ws;        // 12,800,000 B (bf16)
  int* bcnt = (int*)(ws + 12800000);                    //     50,048 B (782*64B)
  int* offs = (int*)(ws + 12850048);                    //      3,136 B (783 ints)
  int* cur  = (int*)(ws + 12853248);                    //     50,048 B
  int2* rec = (int2*)(ws + 12903296);                   // 12,800,000 B (end ~25.7 MB)

  hipMemsetAsync(bcnt, 0, NBKT * CPAD * sizeof(int), stream);

  gcn_gemm<<<(N_NODES + 63) / 64, 256, 0, stream>>>(x, W, support);
  gcn_bhist<<<256, 256, 0, stream>>>(edst, bcnt);
  gcn_bscan<<<1, 1024, 0, stream>>>(bcnt, offs, cur);
  gcn_bfill<<<(N_EDGES + 255) / 256, 256, 0, stream>>>(esrc, edst, ew, cur, rec);
  gcn_baccum<<<NBKT, 256, 0, stream>>>((const unsigned*)support, offs, rec, b, out);
}

// Round 5
// 782.347 us; speedup vs baseline: 1.1120x; 1.1120x over previous
//
#include <hip/hip_runtime.h>
#include <stdint.h>

#define N_NODES 100000
#define N_EDGES 1600000
#define NFEAT 256
#define NHID 64
#define TILE 32                               // dst nodes per bucket
#define NBKT ((N_NODES + TILE - 1) / TILE)    // 3125 (exact: 3125*32 = 100000)
#define CPAD 16                               // cursor padding: 16 ints = 64B line

// ---------------------------------------------------------------------------
// fp32 -> bf16 (round to nearest even)
// ---------------------------------------------------------------------------
__device__ __forceinline__ unsigned short f2bf(float f) {
  unsigned u = __float_as_uint(f);
  u = (u + 0x7FFFu + ((u >> 16) & 1u)) >> 16;
  return (unsigned short)u;
}

// ---------------------------------------------------------------------------
// Kernel 1: support = x @ W  [100000,256] x [256,64], fp32 math, bf16 output
// ---------------------------------------------------------------------------
__global__ __launch_bounds__(256, 2) void gcn_gemm(const float* __restrict__ x,
                                                   const float* __restrict__ W,
                                                   unsigned short* __restrict__ support) {
  __shared__ float xs[64][NFEAT + 4];
  const int tid = threadIdx.x;
  const int row0 = blockIdx.x * 64;

#pragma unroll
  for (int it = 0; it < 16; ++it) {
    int idx = it * 256 + tid;
    int r = idx >> 6;
    int kc = (idx & 63) << 2;
    float4 v = make_float4(0.f, 0.f, 0.f, 0.f);
    if (row0 + r < N_NODES)
      v = *reinterpret_cast<const float4*>(&x[(size_t)(row0 + r) * NFEAT + kc]);
    *reinterpret_cast<float4*>(&xs[r][kc]) = v;
  }
  __syncthreads();

  const int c4 = (tid & 15) << 2;
  const int r4 = (tid >> 4) << 2;
  float acc[4][4];
#pragma unroll
  for (int i = 0; i < 4; ++i)
#pragma unroll
    for (int j = 0; j < 4; ++j) acc[i][j] = 0.f;

  for (int kb = 0; kb < NFEAT; kb += 4) {
    float wv[4][4];
#pragma unroll
    for (int j = 0; j < 4; ++j) {
      float4 t = *reinterpret_cast<const float4*>(&W[(kb + j) * NHID + c4]);
      wv[j][0] = t.x; wv[j][1] = t.y; wv[j][2] = t.z; wv[j][3] = t.w;
    }
    float xv[4][4];
#pragma unroll
    for (int i = 0; i < 4; ++i) {
      float4 t = *reinterpret_cast<const float4*>(&xs[r4 + i][kb]);
      xv[i][0] = t.x; xv[i][1] = t.y; xv[i][2] = t.z; xv[i][3] = t.w;
    }
#pragma unroll
    for (int i = 0; i < 4; ++i)
#pragma unroll
      for (int c = 0; c < 4; ++c)
#pragma unroll
        for (int j = 0; j < 4; ++j)
          acc[i][c] = fmaf(xv[i][j], wv[j][c], acc[i][c]);
  }

#pragma unroll
  for (int i = 0; i < 4; ++i) {
    int r = row0 + r4 + i;
    if (r < N_NODES) {
      ushort4 o;
      o.x = f2bf(acc[i][0]); o.y = f2bf(acc[i][1]);
      o.z = f2bf(acc[i][2]); o.w = f2bf(acc[i][3]);
      *reinterpret_cast<ushort4*>(&support[(size_t)r * NHID + c4]) = o;
    }
  }
}

// ---------------------------------------------------------------------------
// Bucket histogram: LDS pre-aggregation, one global atomic per nonempty bucket
// ---------------------------------------------------------------------------
__global__ __launch_bounds__(256) void gcn_bhist(const int* __restrict__ edst,
                                                 int* __restrict__ bcnt) {
  __shared__ int h[NBKT];
  for (int i = threadIdx.x; i < NBKT; i += 256) h[i] = 0;
  __syncthreads();
  const int stride = gridDim.x * 256;
  for (int e = blockIdx.x * 256 + threadIdx.x; e < N_EDGES; e += stride)
    atomicAdd(&h[edst[e] / TILE], 1);
  __syncthreads();
  for (int i = threadIdx.x; i < NBKT; i += 256) {
    int v = h[i];
    if (v) atomicAdd(&bcnt[i * CPAD], v);
  }
}

// ---------------------------------------------------------------------------
// One-block exclusive scan over NBKT bucket counts (1024 thr x 4 segments)
// ---------------------------------------------------------------------------
__global__ __launch_bounds__(1024) void gcn_bscan(const int* __restrict__ bcnt,
                                                  int* __restrict__ offs,
                                                  int* __restrict__ cur) {
  __shared__ int sh[1024];
  const int t = threadIdx.x;
  int v[4];
  int s = 0;
#pragma unroll
  for (int k = 0; k < 4; ++k) {
    int idx = t * 4 + k;
    v[k] = (idx < NBKT) ? bcnt[idx * CPAD] : 0;
    s += v[k];
  }
  sh[t] = s;
  __syncthreads();
  for (int st = 1; st < 1024; st <<= 1) {
    int a = (t >= st) ? sh[t - st] : 0;
    __syncthreads();
    sh[t] += a;
    __syncthreads();
  }
  int running = sh[t] - s;  // exclusive base for this thread's segment
#pragma unroll
  for (int k = 0; k < 4; ++k) {
    int idx = t * 4 + k;
    if (idx < NBKT) {
      offs[idx] = running;
      cur[idx * CPAD] = running;
    }
    running += v[k];
  }
  if (t == 1023) offs[NBKT] = sh[1023];
}

// ---------------------------------------------------------------------------
// Bucket fill: 3125 clustered write fronts.
// rec.x packs src (17 bits) | dst-low-5 << 17 ; rec.y = weight bits
// ---------------------------------------------------------------------------
__global__ __launch_bounds__(256) void gcn_bfill(const int* __restrict__ esrc,
                                                 const int* __restrict__ edst,
                                                 const float* __restrict__ ew,
                                                 int* __restrict__ cur,
                                                 int2* __restrict__ rec) {
  int e = blockIdx.x * 256 + threadIdx.x;
  if (e >= N_EDGES) return;
  int d = edst[e];
  int b = d / TILE;
  int slot = atomicAdd(&cur[b * CPAD], 1);
  rec[slot] = make_int2(esrc[e] | ((d & (TILE - 1)) << 17), __float_as_int(ew[e]));
}

// ---------------------------------------------------------------------------
// Threefry-2x32-20, key (0,42), counter (0,i); keep iff top bit of x0^x1 clear
// ---------------------------------------------------------------------------
__device__ __forceinline__ unsigned rotl32(unsigned x, int r) {
  return (x << r) | (x >> (32 - r));
}

__device__ __forceinline__ unsigned threefry_bits(unsigned i) {
  const unsigned ks0 = 0u, ks1 = 42u;
  const unsigned ks2 = 0x1BD11BDAu ^ ks0 ^ ks1;
  unsigned x0 = ks0;
  unsigned x1 = i + ks1;
#define TF_R4(a, bb, c, d)                       \
  x0 += x1; x1 = rotl32(x1, a);  x1 ^= x0;       \
  x0 += x1; x1 = rotl32(x1, bb); x1 ^= x0;       \
  x0 += x1; x1 = rotl32(x1, c);  x1 ^= x0;       \
  x0 += x1; x1 = rotl32(x1, d);  x1 ^= x0;
  TF_R4(13, 15, 26, 6);  x0 += ks1; x1 += ks2 + 1u;
  TF_R4(17, 29, 16, 24); x0 += ks2; x1 += ks0 + 2u;
  TF_R4(13, 15, 26, 6);  x0 += ks0; x1 += ks1 + 3u;
  TF_R4(17, 29, 16, 24); x0 += ks1; x1 += ks2 + 4u;
  TF_R4(13, 15, 26, 6);  x0 += ks2; x1 += ks0 + 5u;
#undef TF_R4
  return x0 ^ x1;
}

// ---------------------------------------------------------------------------
// Bucket accumulate + fused epilogue. One block per 32-node bucket (8KB LDS),
// half-wave (32 lanes) per edge, unrolled x2 for MLP. LDS layout interleaved:
// even feats at [row][0..31], odd at [row][32..63] (lane-conflict-free).
// ---------------------------------------------------------------------------
__global__ __launch_bounds__(256) void gcn_baccum(const unsigned* __restrict__ support2,
                                                  const int* __restrict__ offs,
                                                  const int2* __restrict__ rec,
                                                  const float* __restrict__ bias,
                                                  float* __restrict__ out) {
  __shared__ float acc[TILE][NHID];  // 8 KB
  const int t = threadIdx.x;
#pragma unroll
  for (int i = t; i < TILE * NHID; i += 256) ((float*)acc)[i] = 0.f;
  __syncthreads();

  const int bkt = blockIdx.x;
  const int beg = offs[bkt], end = offs[bkt + 1];
  const int hw = t >> 5;   // 0..7, half-wave id
  const int l = t & 31;

  int j = beg + hw;
  for (; j + 8 < end; j += 16) {
    int2 r0 = rec[j];
    int2 r1 = rec[j + 8];
    int src0 = r0.x & 0x1FFFF;
    int src1 = r1.x & 0x1FFFF;
    unsigned p0 = support2[(size_t)src0 * 32 + l];
    unsigned p1 = support2[(size_t)src1 * 32 + l];
    int dl0 = (r0.x >> 17) & (TILE - 1);
    int dl1 = (r1.x >> 17) & (TILE - 1);
    float w0 = __int_as_float(r0.y);
    float w1 = __int_as_float(r1.y);
    atomicAdd(&acc[dl0][l],      __uint_as_float(p0 << 16) * w0);
    atomicAdd(&acc[dl0][32 + l], __uint_as_float(p0 & 0xFFFF0000u) * w0);
    atomicAdd(&acc[dl1][l],      __uint_as_float(p1 << 16) * w1);
    atomicAdd(&acc[dl1][32 + l], __uint_as_float(p1 & 0xFFFF0000u) * w1);
  }
  if (j < end) {
    int2 r0 = rec[j];
    int src0 = r0.x & 0x1FFFF;
    unsigned p0 = support2[(size_t)src0 * 32 + l];
    int dl0 = (r0.x >> 17) & (TILE - 1);
    float w0 = __int_as_float(r0.y);
    atomicAdd(&acc[dl0][l],      __uint_as_float(p0 << 16) * w0);
    atomicAdd(&acc[dl0][32 + l], __uint_as_float(p0 & 0xFFFF0000u) * w0);
  }
  __syncthreads();

  const int row0 = bkt * TILE;
  const int col = t & 63;
  const float bb = bias[col];
  const int widx = ((col & 1) << 5) + (col >> 1);  // de-interleave
#pragma unroll
  for (int r = t >> 6; r < TILE; r += 4) {
    int node = row0 + r;
    float h = fmaxf(acc[r][widx] + bb, 0.f) * 2.0f;
    unsigned i = (unsigned)node * 64u + (unsigned)col;
    unsigned m = threefry_bits(i);
    out[i] = (m & 0x80000000u) ? 0.f : h;
  }
}

// ---------------------------------------------------------------------------
extern "C" void kernel_launch(void* const* d_in, const int* in_sizes, int n_in,
                              void* d_out, int out_size, void* d_ws, size_t ws_size,
                              hipStream_t stream) {
  const float* x = (const float*)d_in[0];
  const float* W = (const float*)d_in[1];
  const float* b = (const float*)d_in[2];
  const int* esrc = (const int*)d_in[3];
  const int* edst = (const int*)d_in[4];
  const float* ew = (const float*)d_in[5];
  float* out = (float*)d_out;

  char* ws = (char*)d_ws;
  unsigned short* support = (unsigned short*)ws;        // 12,800,000 B (bf16)
  int* bcnt = (int*)(ws + 12800000);                    //    200,000 B (3125*64B)
  int* offs = (int*)(ws + 13000000);                    //     12,544 B (3126 ints)
  int* cur  = (int*)(ws + 13012544);                    //    200,000 B
  int2* rec = (int2*)(ws + 13212544);                   // 12,800,000 B (end ~26.0 MB)

  hipMemsetAsync(bcnt, 0, NBKT * CPAD * sizeof(int), stream);

  gcn_gemm<<<(N_NODES + 63) / 64, 256, 0, stream>>>(x, W, support);
  gcn_bhist<<<256, 256, 0, stream>>>(edst, bcnt);
  gcn_bscan<<<1, 1024, 0, stream>>>(bcnt, offs, cur);
  gcn_bfill<<<(N_EDGES + 255) / 256, 256, 0, stream>>>(esrc, edst, ew, cur, rec);
  gcn_baccum<<<NBKT, 256, 0, stream>>>((const unsigned*)support, offs, rec, b, out);
}

// Round 6
// 308.325 us; speedup vs baseline: 2.8215x; 2.5374x over previous
//
#include <hip/hip_runtime.h>
#include <stdint.h>

#define N_NODES 100000
#define N_EDGES 1600000
#define NFEAT 256
#define NHID 64
#define TILE 32                               // dst nodes per bucket
#define NBKT ((N_NODES + TILE - 1) / TILE)    // 3125 (exact: 3125*32 = 100000)
#define CPAD 16                               // cursor padding: 16 ints = 64B line

// ---------------------------------------------------------------------------
// fp32 -> bf16 (round to nearest even)
// ---------------------------------------------------------------------------
__device__ __forceinline__ unsigned short f2bf(float f) {
  unsigned u = __float_as_uint(f);
  u = (u + 0x7FFFu + ((u >> 16) & 1u)) >> 16;
  return (unsigned short)u;
}

// ---------------------------------------------------------------------------
// Kernel 1: support = x @ W  [100000,256] x [256,64], fp32 math, bf16 output
// ---------------------------------------------------------------------------
__global__ __launch_bounds__(256, 2) void gcn_gemm(const float* __restrict__ x,
                                                   const float* __restrict__ W,
                                                   unsigned short* __restrict__ support) {
  __shared__ float xs[64][NFEAT + 4];
  const int tid = threadIdx.x;
  const int row0 = blockIdx.x * 64;

#pragma unroll
  for (int it = 0; it < 16; ++it) {
    int idx = it * 256 + tid;
    int r = idx >> 6;
    int kc = (idx & 63) << 2;
    float4 v = make_float4(0.f, 0.f, 0.f, 0.f);
    if (row0 + r < N_NODES)
      v = *reinterpret_cast<const float4*>(&x[(size_t)(row0 + r) * NFEAT + kc]);
    *reinterpret_cast<float4*>(&xs[r][kc]) = v;
  }
  __syncthreads();

  const int c4 = (tid & 15) << 2;
  const int r4 = (tid >> 4) << 2;
  float acc[4][4];
#pragma unroll
  for (int i = 0; i < 4; ++i)
#pragma unroll
    for (int j = 0; j < 4; ++j) acc[i][j] = 0.f;

  for (int kb = 0; kb < NFEAT; kb += 4) {
    float wv[4][4];
#pragma unroll
    for (int j = 0; j < 4; ++j) {
      float4 t = *reinterpret_cast<const float4*>(&W[(kb + j) * NHID + c4]);
      wv[j][0] = t.x; wv[j][1] = t.y; wv[j][2] = t.z; wv[j][3] = t.w;
    }
    float xv[4][4];
#pragma unroll
    for (int i = 0; i < 4; ++i) {
      float4 t = *reinterpret_cast<const float4*>(&xs[r4 + i][kb]);
      xv[i][0] = t.x; xv[i][1] = t.y; xv[i][2] = t.z; xv[i][3] = t.w;
    }
#pragma unroll
    for (int i = 0; i < 4; ++i)
#pragma unroll
      for (int c = 0; c < 4; ++c)
#pragma unroll
        for (int j = 0; j < 4; ++j)
          acc[i][c] = fmaf(xv[i][j], wv[j][c], acc[i][c]);
  }

#pragma unroll
  for (int i = 0; i < 4; ++i) {
    int r = row0 + r4 + i;
    if (r < N_NODES) {
      ushort4 o;
      o.x = f2bf(acc[i][0]); o.y = f2bf(acc[i][1]);
      o.z = f2bf(acc[i][2]); o.w = f2bf(acc[i][3]);
      *reinterpret_cast<ushort4*>(&support[(size_t)r * NHID + c4]) = o;
    }
  }
}

// ---------------------------------------------------------------------------
// Bucket histogram: LDS pre-aggregation, one global atomic per nonempty bucket
// ---------------------------------------------------------------------------
__global__ __launch_bounds__(256) void gcn_bhist(const int* __restrict__ edst,
                                                 int* __restrict__ bcnt) {
  __shared__ int h[NBKT];
  for (int i = threadIdx.x; i < NBKT; i += 256) h[i] = 0;
  __syncthreads();
  const int stride = gridDim.x * 256;
  for (int e = blockIdx.x * 256 + threadIdx.x; e < N_EDGES; e += stride)
    atomicAdd(&h[edst[e] / TILE], 1);
  __syncthreads();
  for (int i = threadIdx.x; i < NBKT; i += 256) {
    int v = h[i];
    if (v) atomicAdd(&bcnt[i * CPAD], v);
  }
}

// ---------------------------------------------------------------------------
// One-block exclusive scan over NBKT bucket counts (1024 thr x 4 segments)
// ---------------------------------------------------------------------------
__global__ __launch_bounds__(1024) void gcn_bscan(const int* __restrict__ bcnt,
                                                  int* __restrict__ offs,
                                                  int* __restrict__ cur) {
  __shared__ int sh[1024];
  const int t = threadIdx.x;
  int v[4];
  int s = 0;
#pragma unroll
  for (int k = 0; k < 4; ++k) {
    int idx = t * 4 + k;
    v[k] = (idx < NBKT) ? bcnt[idx * CPAD] : 0;
    s += v[k];
  }
  sh[t] = s;
  __syncthreads();
  for (int st = 1; st < 1024; st <<= 1) {
    int a = (t >= st) ? sh[t - st] : 0;
    __syncthreads();
    sh[t] += a;
    __syncthreads();
  }
  int running = sh[t] - s;  // exclusive base for this thread's segment
#pragma unroll
  for (int k = 0; k < 4; ++k) {
    int idx = t * 4 + k;
    if (idx < NBKT) {
      offs[idx] = running;
      cur[idx * CPAD] = running;
    }
    running += v[k];
  }
  if (t == 1023) offs[NBKT] = sh[1023];
}

// ---------------------------------------------------------------------------
// Bucket fill: 3125 clustered write fronts (writes L2-coalesce, ~25MB to HBM).
// rec.x packs src (17 bits) | dst-low-5 << 17 ; rec.y = weight bits
// ---------------------------------------------------------------------------
__global__ __launch_bounds__(256) void gcn_bfill(const int* __restrict__ esrc,
                                                 const int* __restrict__ edst,
                                                 const float* __restrict__ ew,
                                                 int* __restrict__ cur,
                                                 int2* __restrict__ rec) {
  int e = blockIdx.x * 256 + threadIdx.x;
  if (e >= N_EDGES) return;
  int d = edst[e];
  int b = d / TILE;
  int slot = atomicAdd(&cur[b * CPAD], 1);
  rec[slot] = make_int2(esrc[e] | ((d & (TILE - 1)) << 17), __float_as_int(ew[e]));
}

// ---------------------------------------------------------------------------
// Per-bucket counting sort (32 bins): rec (bucket-ordered) -> rec2
// (node-ordered); emits per-node [nodeoff, nodeend). All writes confined to
// the bucket's 4KB window (L2-resident) or coalesced.
// ---------------------------------------------------------------------------
__global__ __launch_bounds__(256) void gcn_bsort(const int* __restrict__ offs,
                                                 const int2* __restrict__ rec,
                                                 int2* __restrict__ rec2,
                                                 int* __restrict__ nodeoff,
                                                 int* __restrict__ nodeend) {
  __shared__ int cnt[TILE];
  __shared__ int base[TILE];
  const int t = threadIdx.x;
  const int b = blockIdx.x;
  const int beg = offs[b], end = offs[b + 1];

  if (t < TILE) cnt[t] = 0;
  __syncthreads();
  for (int j = beg + t; j < end; j += 256)
    atomicAdd(&cnt[(rec[j].x >> 17) & (TILE - 1)], 1);
  __syncthreads();
  if (t == 0) {
    int run = beg;
#pragma unroll
    for (int i = 0; i < TILE; ++i) {
      base[i] = run;
      run += cnt[i];
    }
  }
  __syncthreads();
  if (t < TILE) {
    int node = b * TILE + t;
    nodeoff[node] = base[t];
    nodeend[node] = base[t] + cnt[t];
  }
  __syncthreads();
  if (t < TILE) cnt[t] = base[t];  // reuse as cursors
  __syncthreads();
  for (int j = beg + t; j < end; j += 256) {
    int2 r = rec[j];
    int slot = atomicAdd(&cnt[(r.x >> 17) & (TILE - 1)], 1);
    rec2[slot] = r;
  }
}

// ---------------------------------------------------------------------------
// Threefry-2x32-20, key (0,42), counter (0,i); keep iff top bit of x0^x1 clear
// ---------------------------------------------------------------------------
__device__ __forceinline__ unsigned rotl32(unsigned x, int r) {
  return (x << r) | (x >> (32 - r));
}

__device__ __forceinline__ unsigned threefry_bits(unsigned i) {
  const unsigned ks0 = 0u, ks1 = 42u;
  const unsigned ks2 = 0x1BD11BDAu ^ ks0 ^ ks1;
  unsigned x0 = ks0;
  unsigned x1 = i + ks1;
#define TF_R4(a, bb, c, d)                       \
  x0 += x1; x1 = rotl32(x1, a);  x1 ^= x0;       \
  x0 += x1; x1 = rotl32(x1, bb); x1 ^= x0;       \
  x0 += x1; x1 = rotl32(x1, c);  x1 ^= x0;       \
  x0 += x1; x1 = rotl32(x1, d);  x1 ^= x0;
  TF_R4(13, 15, 26, 6);  x0 += ks1; x1 += ks2 + 1u;
  TF_R4(17, 29, 16, 24); x0 += ks2; x1 += ks0 + 2u;
  TF_R4(13, 15, 26, 6);  x0 += ks0; x1 += ks1 + 3u;
  TF_R4(17, 29, 16, 24); x0 += ks1; x1 += ks2 + 4u;
  TF_R4(13, 15, 26, 6);  x0 += ks2; x1 += ks0 + 5u;
#undef TF_R4
  return x0 ^ x1;
}

// ---------------------------------------------------------------------------
// Pull + finalize (round-3 proven structure): half-wave (32 lanes) per dst
// node; lane = 2 features (bf16 pair), register accumulate, unroll x2.
// ---------------------------------------------------------------------------
__global__ __launch_bounds__(256) void gcn_pull(const unsigned* __restrict__ support2,
                                                const int* __restrict__ nodeoff,
                                                const int* __restrict__ nodeend,
                                                const int2* __restrict__ rec2,
                                                const float* __restrict__ b,
                                                float* __restrict__ out) {
  const int half = threadIdx.x >> 5;          // node slot within block (0..7)
  const int l = threadIdx.x & 31;             // lane within half-wave
  const int d = blockIdx.x * 8 + half;
  if (d >= N_NODES) return;

  const int off = nodeoff[d];
  const int end = nodeend[d];
  float acc0 = 0.f, acc1 = 0.f;

  int j = off;
  for (; j + 1 < end; j += 2) {
    int2 r0 = rec2[j];
    int2 r1 = rec2[j + 1];
    int s0 = r0.x & 0x1FFFF;
    int s1 = r1.x & 0x1FFFF;
    unsigned p0 = support2[(size_t)s0 * 32 + l];
    unsigned p1 = support2[(size_t)s1 * 32 + l];
    float w0 = __int_as_float(r0.y);
    float w1 = __int_as_float(r1.y);
    acc0 = fmaf(__uint_as_float(p0 << 16), w0, acc0);
    acc1 = fmaf(__uint_as_float(p0 & 0xFFFF0000u), w0, acc1);
    acc0 = fmaf(__uint_as_float(p1 << 16), w1, acc0);
    acc1 = fmaf(__uint_as_float(p1 & 0xFFFF0000u), w1, acc1);
  }
  if (j < end) {
    int2 r0 = rec2[j];
    int s0 = r0.x & 0x1FFFF;
    unsigned p0 = support2[(size_t)s0 * 32 + l];
    float w0 = __int_as_float(r0.y);
    acc0 = fmaf(__uint_as_float(p0 << 16), w0, acc0);
    acc1 = fmaf(__uint_as_float(p0 & 0xFFFF0000u), w0, acc1);
  }

  const int f = l * 2;
  float2 bb = *reinterpret_cast<const float2*>(&b[f]);
  float h0 = fmaxf(acc0 + bb.x, 0.f) * 2.0f;
  float h1 = fmaxf(acc1 + bb.y, 0.f) * 2.0f;
  unsigned i0 = (unsigned)d * 64u + (unsigned)f;
  unsigned m0 = threefry_bits(i0);
  unsigned m1 = threefry_bits(i0 + 1u);
  float2 o;
  o.x = (m0 & 0x80000000u) ? 0.f : h0;
  o.y = (m1 & 0x80000000u) ? 0.f : h1;
  *reinterpret_cast<float2*>(&out[i0]) = o;
}

// ---------------------------------------------------------------------------
extern "C" void kernel_launch(void* const* d_in, const int* in_sizes, int n_in,
                              void* d_out, int out_size, void* d_ws, size_t ws_size,
                              hipStream_t stream) {
  const float* x = (const float*)d_in[0];
  const float* W = (const float*)d_in[1];
  const float* b = (const float*)d_in[2];
  const int* esrc = (const int*)d_in[3];
  const int* edst = (const int*)d_in[4];
  const float* ew = (const float*)d_in[5];
  float* out = (float*)d_out;

  char* ws = (char*)d_ws;
  unsigned short* support = (unsigned short*)ws;        // 12,800,000 B (bf16)
  int* bcnt    = (int*)(ws + 12800000);                 //    200,000 B
  int* offs    = (int*)(ws + 13000000);                 //     12,544 B
  int* cur     = (int*)(ws + 13012544);                 //    200,000 B
  int2* rec    = (int2*)(ws + 13212544);                // 12,800,000 B
  int2* rec2   = (int2*)(ws + 26012544);                // 12,800,000 B
  int* nodeoff = (int*)(ws + 38812544);                 //    400,000 B
  int* nodeend = (int*)(ws + 39212544);                 //    400,000 B  (end ~39.6 MB)

  hipMemsetAsync(bcnt, 0, NBKT * CPAD * sizeof(int), stream);

  gcn_gemm<<<(N_NODES + 63) / 64, 256, 0, stream>>>(x, W, support);
  gcn_bhist<<<256, 256, 0, stream>>>(edst, bcnt);
  gcn_bscan<<<1, 1024, 0, stream>>>(bcnt, offs, cur);
  gcn_bfill<<<(N_EDGES + 255) / 256, 256, 0, stream>>>(esrc, edst, ew, cur, rec);
  gcn_bsort<<<NBKT, 256, 0, stream>>>(offs, rec, rec2, nodeoff, nodeend);
  gcn_pull<<<(N_NODES + 7) / 8, 256, 0, stream>>>((const unsigned*)support, nodeoff,
                                                  nodeend, rec2, b, out);
}

// Round 7
// 209.256 us; speedup vs baseline: 4.1573x; 1.4734x over previous
//
#include <hip/hip_runtime.h>
#include <stdint.h>

#define N_NODES 100000
#define N_EDGES 1600000
#define NFEAT 256
#define NHID 64
#define TILE 32                               // dst nodes per bucket
#define NBKT ((N_NODES + TILE - 1) / TILE)    // 3125 (exact: 3125*32 = 100000)
#define SLICES 8                              // ~XCD count; slice = blockIdx & 7
#define CAP 128                               // records per (bucket,slice) cell
#define BUFCAP 832                            // LDS records per bucket (mean 512, +14 sigma)

// ---------------------------------------------------------------------------
// fp32 -> bf16 (round to nearest even)
// ---------------------------------------------------------------------------
__device__ __forceinline__ unsigned short f2bf(float f) {
  unsigned u = __float_as_uint(f);
  u = (u + 0x7FFFu + ((u >> 16) & 1u)) >> 16;
  return (unsigned short)u;
}

// ---------------------------------------------------------------------------
// Kernel 1: support = x @ W  [100000,256] x [256,64], fp32 math, bf16 output
// ---------------------------------------------------------------------------
__global__ __launch_bounds__(256, 2) void gcn_gemm(const float* __restrict__ x,
                                                   const float* __restrict__ W,
                                                   unsigned short* __restrict__ support) {
  __shared__ float xs[64][NFEAT + 4];
  const int tid = threadIdx.x;
  const int row0 = blockIdx.x * 64;

#pragma unroll
  for (int it = 0; it < 16; ++it) {
    int idx = it * 256 + tid;
    int r = idx >> 6;
    int kc = (idx & 63) << 2;
    float4 v = make_float4(0.f, 0.f, 0.f, 0.f);
    if (row0 + r < N_NODES)
      v = *reinterpret_cast<const float4*>(&x[(size_t)(row0 + r) * NFEAT + kc]);
    *reinterpret_cast<float4*>(&xs[r][kc]) = v;
  }
  __syncthreads();

  const int c4 = (tid & 15) << 2;
  const int r4 = (tid >> 4) << 2;
  float acc[4][4];
#pragma unroll
  for (int i = 0; i < 4; ++i)
#pragma unroll
    for (int j = 0; j < 4; ++j) acc[i][j] = 0.f;

  for (int kb = 0; kb < NFEAT; kb += 4) {
    float wv[4][4];
#pragma unroll
    for (int j = 0; j < 4; ++j) {
      float4 t = *reinterpret_cast<const float4*>(&W[(kb + j) * NHID + c4]);
      wv[j][0] = t.x; wv[j][1] = t.y; wv[j][2] = t.z; wv[j][3] = t.w;
    }
    float xv[4][4];
#pragma unroll
    for (int i = 0; i < 4; ++i) {
      float4 t = *reinterpret_cast<const float4*>(&xs[r4 + i][kb]);
      xv[i][0] = t.x; xv[i][1] = t.y; xv[i][2] = t.z; xv[i][3] = t.w;
    }
#pragma unroll
    for (int i = 0; i < 4; ++i)
#pragma unroll
      for (int c = 0; c < 4; ++c)
#pragma unroll
        for (int j = 0; j < 4; ++j)
          acc[i][c] = fmaf(xv[i][j], wv[j][c], acc[i][c]);
  }

#pragma unroll
  for (int i = 0; i < 4; ++i) {
    int r = row0 + r4 + i;
    if (r < N_NODES) {
      ushort4 o;
      o.x = f2bf(acc[i][0]); o.y = f2bf(acc[i][1]);
      o.z = f2bf(acc[i][2]); o.w = f2bf(acc[i][3]);
      *reinterpret_cast<ushort4*>(&support[(size_t)r * NHID + c4]) = o;
    }
  }
}

// ---------------------------------------------------------------------------
// Sliced bucket fill. slice = blockIdx & 7 (~XCD id): each (bucket,slice)
// cell's cursor and 1KB record region are touched by ONE XCD only ->
// L2-local atomics, sequential full-line fills. No histogram/scan needed.
// cnt layout: slice-major cnt[s*NBKT + b]. cell base: (b*SLICES+s)*CAP.
// rec.x packs src (17 bits) | dst-low-5 << 17 ; rec.y = weight bits.
// ---------------------------------------------------------------------------
__global__ __launch_bounds__(256) void gcn_bfill(const int* __restrict__ esrc,
                                                 const int* __restrict__ edst,
                                                 const float* __restrict__ ew,
                                                 int* __restrict__ cnt,
                                                 int2* __restrict__ rec) {
  int e = blockIdx.x * 256 + threadIdx.x;
  if (e >= N_EDGES) return;
  const int s = blockIdx.x & (SLICES - 1);
  int d = edst[e];
  int b = d >> 5;  // d / TILE
  int slot = atomicAdd(&cnt[s * NBKT + b], 1);  // XCD-local L2 atomic
  rec[(size_t)(b * SLICES + s) * CAP + slot] =
      make_int2(esrc[e] | ((d & (TILE - 1)) << 17), __float_as_int(ew[e]));
}

// ---------------------------------------------------------------------------
// Threefry-2x32-20, key (0,42), counter (0,i); keep iff top bit of x0^x1 clear
// ---------------------------------------------------------------------------
__device__ __forceinline__ unsigned rotl32(unsigned x, int r) {
  return (x << r) | (x >> (32 - r));
}

__device__ __forceinline__ unsigned threefry_bits(unsigned i) {
  const unsigned ks0 = 0u, ks1 = 42u;
  const unsigned ks2 = 0x1BD11BDAu ^ ks0 ^ ks1;
  unsigned x0 = ks0;
  unsigned x1 = i + ks1;
#define TF_R4(a, bb, c, d)                       \
  x0 += x1; x1 = rotl32(x1, a);  x1 ^= x0;       \
  x0 += x1; x1 = rotl32(x1, bb); x1 ^= x0;       \
  x0 += x1; x1 = rotl32(x1, c);  x1 ^= x0;       \
  x0 += x1; x1 = rotl32(x1, d);  x1 ^= x0;
  TF_R4(13, 15, 26, 6);  x0 += ks1; x1 += ks2 + 1u;
  TF_R4(17, 29, 16, 24); x0 += ks2; x1 += ks0 + 2u;
  TF_R4(13, 15, 26, 6);  x0 += ks0; x1 += ks1 + 3u;
  TF_R4(17, 29, 16, 24); x0 += ks1; x1 += ks2 + 4u;
  TF_R4(13, 15, 26, 6);  x0 += ks2; x1 += ks0 + 5u;
#undef TF_R4
  return x0 ^ x1;
}

// ---------------------------------------------------------------------------
// Fused per-bucket counting sort (in LDS) + register pull + epilogue.
// One block per 32-node bucket: read the bucket's 8 cells (contiguous 8KB),
// group records by node into LDS buf, then half-wave per node: lane = bf16
// feature pair, register accumulate, bias+relu+threefry dropout, store.
// ---------------------------------------------------------------------------
__global__ __launch_bounds__(256) void gcn_pull_fused(const unsigned* __restrict__ support2,
                                                      const int* __restrict__ cnt,
                                                      const int2* __restrict__ rec,
                                                      const float* __restrict__ bias,
                                                      float* __restrict__ out) {
  __shared__ int ccnt[SLICES];
  __shared__ int cntl[TILE];
  __shared__ int base[TILE];
  __shared__ int cur[TILE];
  __shared__ int2 buf[BUFCAP];

  const int t = threadIdx.x;
  const int b = blockIdx.x;

  if (t < SLICES) ccnt[t] = cnt[t * NBKT + b];
  if (t < TILE) cntl[t] = 0;
  __syncthreads();

  // pass 1: per-node counts
  const int2* bucket_base = &rec[(size_t)b * SLICES * CAP];
#pragma unroll
  for (int s = 0; s < SLICES; ++s) {
    int n = ccnt[s];
    const int2* cell = bucket_base + s * CAP;
    for (int j = t; j < n; j += 256)
      atomicAdd(&cntl[(cell[j].x >> 17) & (TILE - 1)], 1);
  }
  __syncthreads();
  if (t == 0) {
    int run = 0;
#pragma unroll
    for (int i = 0; i < TILE; ++i) {
      base[i] = run;
      run += cntl[i];
    }
  }
  __syncthreads();
  if (t < TILE) cur[t] = base[t];
  __syncthreads();

  // pass 2: scatter into node-grouped LDS buffer (order within node arbitrary)
#pragma unroll
  for (int s = 0; s < SLICES; ++s) {
    int n = ccnt[s];
    const int2* cell = bucket_base + s * CAP;
    for (int j = t; j < n; j += 256) {
      int2 r = cell[j];
      int slot = atomicAdd(&cur[(r.x >> 17) & (TILE - 1)], 1);
      buf[slot] = r;
    }
  }
  __syncthreads();

  // pull phase: half-wave per node, 4 nodes per half-wave
  const int hw = t >> 5;
  const int l = t & 31;
  const int f = l * 2;
  const float2 bb = *reinterpret_cast<const float2*>(&bias[f]);

#pragma unroll
  for (int ns = 0; ns < 4; ++ns) {
    const int nl = hw + ns * 8;          // local node 0..31
    const int node = b * TILE + nl;
    int j = base[nl];
    const int end = j + cntl[nl];
    float acc0 = 0.f, acc1 = 0.f;
    for (; j + 1 < end; j += 2) {
      int2 r0 = buf[j];
      int2 r1 = buf[j + 1];
      unsigned p0 = support2[(size_t)(r0.x & 0x1FFFF) * 32 + l];
      unsigned p1 = support2[(size_t)(r1.x & 0x1FFFF) * 32 + l];
      float w0 = __int_as_float(r0.y);
      float w1 = __int_as_float(r1.y);
      acc0 = fmaf(__uint_as_float(p0 << 16), w0, acc0);
      acc1 = fmaf(__uint_as_float(p0 & 0xFFFF0000u), w0, acc1);
      acc0 = fmaf(__uint_as_float(p1 << 16), w1, acc0);
      acc1 = fmaf(__uint_as_float(p1 & 0xFFFF0000u), w1, acc1);
    }
    if (j < end) {
      int2 r0 = buf[j];
      unsigned p0 = support2[(size_t)(r0.x & 0x1FFFF) * 32 + l];
      float w0 = __int_as_float(r0.y);
      acc0 = fmaf(__uint_as_float(p0 << 16), w0, acc0);
      acc1 = fmaf(__uint_as_float(p0 & 0xFFFF0000u), w0, acc1);
    }

    float h0 = fmaxf(acc0 + bb.x, 0.f) * 2.0f;
    float h1 = fmaxf(acc1 + bb.y, 0.f) * 2.0f;
    unsigned i0 = (unsigned)node * 64u + (unsigned)f;
    unsigned m0 = threefry_bits(i0);
    unsigned m1 = threefry_bits(i0 + 1u);
    float2 o;
    o.x = (m0 & 0x80000000u) ? 0.f : h0;
    o.y = (m1 & 0x80000000u) ? 0.f : h1;
    *reinterpret_cast<float2*>(&out[i0]) = o;
  }
}

// ---------------------------------------------------------------------------
extern "C" void kernel_launch(void* const* d_in, const int* in_sizes, int n_in,
                              void* d_out, int out_size, void* d_ws, size_t ws_size,
                              hipStream_t stream) {
  const float* x = (const float*)d_in[0];
  const float* W = (const float*)d_in[1];
  const float* b = (const float*)d_in[2];
  const int* esrc = (const int*)d_in[3];
  const int* edst = (const int*)d_in[4];
  const float* ew = (const float*)d_in[5];
  float* out = (float*)d_out;

  char* ws = (char*)d_ws;
  unsigned short* support = (unsigned short*)ws;   // 12,800,000 B (bf16)
  int* cnt = (int*)(ws + 12800000);                //    100,000 B (8 x 3125)
  int2* rec = (int2*)(ws + 12900000);              // 25,600,000 B (end 38.5 MB)

  hipMemsetAsync(cnt, 0, SLICES * NBKT * sizeof(int), stream);

  gcn_gemm<<<(N_NODES + 63) / 64, 256, 0, stream>>>(x, W, support);
  gcn_bfill<<<(N_EDGES + 255) / 256, 256, 0, stream>>>(esrc, edst, ew, cnt, rec);
  gcn_pull_fused<<<NBKT, 256, 0, stream>>>((const unsigned*)support, cnt, rec, b, out);
}

// Round 8
// 159.409 us; speedup vs baseline: 5.4573x; 1.3127x over previous
//
#include <hip/hip_runtime.h>
#include <stdint.h>

#define N_NODES 100000
#define N_EDGES 1600000
#define NFEAT 256
#define NHID 64
#define TILE 32                               // dst nodes per bucket
#define NBKT ((N_NODES + TILE - 1) / TILE)    // 3125 (exact: 3125*32 = 100000)
#define SLICES 8                              // ~XCD count; slice = blockIdx & 7
#define CAP 128                               // records per (bucket,slice) cell
#define BUFCAP 832                            // LDS records per bucket

typedef __attribute__((ext_vector_type(8))) short sh8;   // 8 bf16 (4 VGPRs)
typedef __attribute__((ext_vector_type(4))) float f4;    // MFMA accumulator

// ---------------------------------------------------------------------------
// fp32 -> bf16 (round to nearest even)
// ---------------------------------------------------------------------------
__device__ __forceinline__ unsigned short f2bf(float f) {
  unsigned u = __float_as_uint(f);
  u = (u + 0x7FFFu + ((u >> 16) & 1u)) >> 16;
  return (unsigned short)u;
}

// ---------------------------------------------------------------------------
// Kernel 1: support = x @ W via mfma_f32_16x16x32_bf16.
// Block = 4 waves x 16 rows = 64 rows. W staged once per block in LDS as
// bf16 transposed Wt[col][k] (pad 264: 2-way bank conflict = free).
// x read global->VGPR (read-once), cvt to bf16 in-register.
// ---------------------------------------------------------------------------
__global__ __launch_bounds__(256) void gcn_gemm_mfma(const float* __restrict__ x,
                                                     const float* __restrict__ W,
                                                     unsigned short* __restrict__ support) {
  __shared__ short Wt[NHID][264];  // 33,792 B
  const int tid = threadIdx.x;

  for (int i = tid; i < NFEAT * NHID; i += 256) {
    int k = i >> 6, c = i & 63;
    Wt[c][k] = (short)f2bf(W[i]);
  }
  __syncthreads();

  const int w = tid >> 6;     // wave 0..3
  const int l = tid & 63;
  const int r16 = l & 15;     // row within 16 (A) / col within 16 (B)
  const int kg = l >> 4;      // k-group 0..3

  const int row = blockIdx.x * 64 + w * 16 + r16;
  const int rowc = row < N_NODES ? row : N_NODES - 1;
  const float* xr = x + (size_t)rowc * NFEAT;

  const f4 z = {0.f, 0.f, 0.f, 0.f};
  f4 acc0 = z, acc1 = z, acc2 = z, acc3 = z;

#pragma unroll
  for (int ks = 0; ks < 8; ++ks) {
    const int k0 = ks * 32 + kg * 8;
    float4 v0 = *reinterpret_cast<const float4*>(&xr[k0]);
    float4 v1 = *reinterpret_cast<const float4*>(&xr[k0 + 4]);
    sh8 a;
    a[0] = (short)f2bf(v0.x); a[1] = (short)f2bf(v0.y);
    a[2] = (short)f2bf(v0.z); a[3] = (short)f2bf(v0.w);
    a[4] = (short)f2bf(v1.x); a[5] = (short)f2bf(v1.y);
    a[6] = (short)f2bf(v1.z); a[7] = (short)f2bf(v1.w);

    sh8 b0 = *reinterpret_cast<const sh8*>(&Wt[r16][k0]);
    sh8 b1 = *reinterpret_cast<const sh8*>(&Wt[16 + r16][k0]);
    sh8 b2 = *reinterpret_cast<const sh8*>(&Wt[32 + r16][k0]);
    sh8 b3 = *reinterpret_cast<const sh8*>(&Wt[48 + r16][k0]);
    acc0 = __builtin_amdgcn_mfma_f32_16x16x32_bf16(a, b0, acc0, 0, 0, 0);
    acc1 = __builtin_amdgcn_mfma_f32_16x16x32_bf16(a, b1, acc1, 0, 0, 0);
    acc2 = __builtin_amdgcn_mfma_f32_16x16x32_bf16(a, b2, acc2, 0, 0, 0);
    acc3 = __builtin_amdgcn_mfma_f32_16x16x32_bf16(a, b3, acc3, 0, 0, 0);
  }

  // C/D layout: row = (lane>>4)*4 + reg, col = lane&15
  const int orow_base = blockIdx.x * 64 + w * 16 + kg * 4;
#pragma unroll
  for (int reg = 0; reg < 4; ++reg) {
    const int orow = orow_base + reg;
    if (orow < N_NODES) {
      unsigned short* sp = &support[(size_t)orow * NHID + r16];
      sp[0]  = f2bf(acc0[reg]);
      sp[16] = f2bf(acc1[reg]);
      sp[32] = f2bf(acc2[reg]);
      sp[48] = f2bf(acc3[reg]);
    }
  }
}

// ---------------------------------------------------------------------------
// Sliced bucket fill. slice = blockIdx & 7 (~XCD id): each (bucket,slice)
// cell's cursor and 1KB record region are touched by ONE XCD only ->
// L2-local atomics, sequential full-line fills.
// rec.x packs src (17 bits) | dst-low-5 << 17 ; rec.y = weight bits.
// ---------------------------------------------------------------------------
__global__ __launch_bounds__(256) void gcn_bfill(const int* __restrict__ esrc,
                                                 const int* __restrict__ edst,
                                                 const float* __restrict__ ew,
                                                 int* __restrict__ cnt,
                                                 int2* __restrict__ rec) {
  int e = blockIdx.x * 256 + threadIdx.x;
  if (e >= N_EDGES) return;
  const int s = blockIdx.x & (SLICES - 1);
  int d = edst[e];
  int b = d >> 5;  // d / TILE
  int slot = atomicAdd(&cnt[s * NBKT + b], 1);  // XCD-local L2 atomic
  rec[(size_t)(b * SLICES + s) * CAP + slot] =
      make_int2(esrc[e] | ((d & (TILE - 1)) << 17), __float_as_int(ew[e]));
}

// ---------------------------------------------------------------------------
// Threefry-2x32-20, key (0,42), counter (0,i); keep iff top bit of x0^x1 clear
// ---------------------------------------------------------------------------
__device__ __forceinline__ unsigned rotl32(unsigned x, int r) {
  return (x << r) | (x >> (32 - r));
}

__device__ __forceinline__ unsigned threefry_bits(unsigned i) {
  const unsigned ks0 = 0u, ks1 = 42u;
  const unsigned ks2 = 0x1BD11BDAu ^ ks0 ^ ks1;
  unsigned x0 = ks0;
  unsigned x1 = i + ks1;
#define TF_R4(a, bb, c, d)                       \
  x0 += x1; x1 = rotl32(x1, a);  x1 ^= x0;       \
  x0 += x1; x1 = rotl32(x1, bb); x1 ^= x0;       \
  x0 += x1; x1 = rotl32(x1, c);  x1 ^= x0;       \
  x0 += x1; x1 = rotl32(x1, d);  x1 ^= x0;
  TF_R4(13, 15, 26, 6);  x0 += ks1; x1 += ks2 + 1u;
  TF_R4(17, 29, 16, 24); x0 += ks2; x1 += ks0 + 2u;
  TF_R4(13, 15, 26, 6);  x0 += ks0; x1 += ks1 + 3u;
  TF_R4(17, 29, 16, 24); x0 += ks1; x1 += ks2 + 4u;
  TF_R4(13, 15, 26, 6);  x0 += ks2; x1 += ks0 + 5u;
#undef TF_R4
  return x0 ^ x1;
}

// ---------------------------------------------------------------------------
// Fused per-bucket counting sort (in LDS) + register pull + epilogue.
// ---------------------------------------------------------------------------
__global__ __launch_bounds__(256) void gcn_pull_fused(const unsigned* __restrict__ support2,
                                                      const int* __restrict__ cnt,
                                                      const int2* __restrict__ rec,
                                                      const float* __restrict__ bias,
                                                      float* __restrict__ out) {
  __shared__ int ccnt[SLICES];
  __shared__ int cntl[TILE];
  __shared__ int base[TILE];
  __shared__ int cur[TILE];
  __shared__ int2 buf[BUFCAP];

  const int t = threadIdx.x;
  const int b = blockIdx.x;

  if (t < SLICES) ccnt[t] = cnt[t * NBKT + b];
  if (t < TILE) cntl[t] = 0;
  __syncthreads();

  // pass 1: per-node counts
  const int2* bucket_base = &rec[(size_t)b * SLICES * CAP];
#pragma unroll
  for (int s = 0; s < SLICES; ++s) {
    int n = ccnt[s];
    const int2* cell = bucket_base + s * CAP;
    for (int j = t; j < n; j += 256)
      atomicAdd(&cntl[(cell[j].x >> 17) & (TILE - 1)], 1);
  }
  __syncthreads();
  if (t == 0) {
    int run = 0;
#pragma unroll
    for (int i = 0; i < TILE; ++i) {
      base[i] = run;
      run += cntl[i];
    }
  }
  __syncthreads();
  if (t < TILE) cur[t] = base[t];
  __syncthreads();

  // pass 2: scatter into node-grouped LDS buffer
#pragma unroll
  for (int s = 0; s < SLICES; ++s) {
    int n = ccnt[s];
    const int2* cell = bucket_base + s * CAP;
    for (int j = t; j < n; j += 256) {
      int2 r = cell[j];
      int slot = atomicAdd(&cur[(r.x >> 17) & (TILE - 1)], 1);
      buf[slot] = r;
    }
  }
  __syncthreads();

  // pull phase: half-wave per node, 4 nodes per half-wave
  const int hw = t >> 5;
  const int l = t & 31;
  const int f = l * 2;
  const float2 bb = *reinterpret_cast<const float2*>(&bias[f]);

#pragma unroll
  for (int ns = 0; ns < 4; ++ns) {
    const int nl = hw + ns * 8;          // local node 0..31
    const int node = b * TILE + nl;
    int j = base[nl];
    const int end = j + cntl[nl];
    float acc0 = 0.f, acc1 = 0.f;
    for (; j + 1 < end; j += 2) {
      int2 r0 = buf[j];
      int2 r1 = buf[j + 1];
      unsigned p0 = support2[(size_t)(r0.x & 0x1FFFF) * 32 + l];
      unsigned p1 = support2[(size_t)(r1.x & 0x1FFFF) * 32 + l];
      float w0 = __int_as_float(r0.y);
      float w1 = __int_as_float(r1.y);
      acc0 = fmaf(__uint_as_float(p0 << 16), w0, acc0);
      acc1 = fmaf(__uint_as_float(p0 & 0xFFFF0000u), w0, acc1);
      acc0 = fmaf(__uint_as_float(p1 << 16), w1, acc0);
      acc1 = fmaf(__uint_as_float(p1 & 0xFFFF0000u), w1, acc1);
    }
    if (j < end) {
      int2 r0 = buf[j];
      unsigned p0 = support2[(size_t)(r0.x & 0x1FFFF) * 32 + l];
      float w0 = __int_as_float(r0.y);
      acc0 = fmaf(__uint_as_float(p0 << 16), w0, acc0);
      acc1 = fmaf(__uint_as_float(p0 & 0xFFFF0000u), w0, acc1);
    }

    float h0 = fmaxf(acc0 + bb.x, 0.f) * 2.0f;
    float h1 = fmaxf(acc1 + bb.y, 0.f) * 2.0f;
    unsigned i0 = (unsigned)node * 64u + (unsigned)f;
    unsigned m0 = threefry_bits(i0);
    unsigned m1 = threefry_bits(i0 + 1u);
    float2 o;
    o.x = (m0 & 0x80000000u) ? 0.f : h0;
    o.y = (m1 & 0x80000000u) ? 0.f : h1;
    *reinterpret_cast<float2*>(&out[i0]) = o;
  }
}

// ---------------------------------------------------------------------------
extern "C" void kernel_launch(void* const* d_in, const int* in_sizes, int n_in,
                              void* d_out, int out_size, void* d_ws, size_t ws_size,
                              hipStream_t stream) {
  const float* x = (const float*)d_in[0];
  const float* W = (const float*)d_in[1];
  const float* b = (const float*)d_in[2];
  const int* esrc = (const int*)d_in[3];
  const int* edst = (const int*)d_in[4];
  const float* ew = (const float*)d_in[5];
  float* out = (float*)d_out;

  char* ws = (char*)d_ws;
  unsigned short* support = (unsigned short*)ws;   // 12,800,000 B (bf16)
  int* cnt = (int*)(ws + 12800000);                //    100,000 B (8 x 3125)
  int2* rec = (int2*)(ws + 12900000);              // 25,600,000 B (end 38.5 MB)

  hipMemsetAsync(cnt, 0, SLICES * NBKT * sizeof(int), stream);

  gcn_gemm_mfma<<<(N_NODES + 63) / 64, 256, 0, stream>>>(x, W, support);
  gcn_bfill<<<(N_EDGES + 255) / 256, 256, 0, stream>>>(esrc, edst, ew, cnt, rec);
  gcn_pull_fused<<<NBKT, 256, 0, stream>>>((const unsigned*)support, cnt, rec, b, out);
}